// Round 10
// baseline (286.407 us; speedup 1.0000x reference)
//
#include <hip/hip_runtime.h>
#include <hip/hip_bf16.h>
#include <math.h>

// Problem constants: x [8,64,64,64] fp32 NCHW, W_std [64,64,3,3] fp32 OIHW.
#define BB 8
#define CC 64
#define HH 64
#define WW 64
#define NPIX (HH*WW)   // 4096
#define LOG2E 1.44269504088896340736f

typedef __attribute__((ext_vector_type(8))) short bf16x8;            // MFMA A/B frag
typedef __attribute__((ext_vector_type(4))) float floatx4;           // MFMA C/D frag
typedef __attribute__((ext_vector_type(8))) unsigned short ushort8;  // 16B unit

__device__ inline unsigned short f2bf(float x) {
  __hip_bfloat16 h = __float2bfloat16(x);
  return *reinterpret_cast<unsigned short*>(&h);
}
__device__ inline float bf2f(unsigned short u) {
  __hip_bfloat16 h = *reinterpret_cast<__hip_bfloat16*>(&u);
  return __bfloat162float(h);
}

// XOR swizzle: 16B channel-chunks permuted within each 128B row so MFMA
// fragment reads from LDS (lane stride 128B) spread across all 32 banks.
__device__ inline int swzoff(int n, int c) {
  return (((c >> 3) ^ (n & 7)) << 3) | (c & 7);
}
__device__ inline int swzvslot(int key, int c) {
  return (((key >> 3) ^ (c & 7)) << 3) | (key & 7);
}

// 16B global -> LDS DMA
#define GLD_LDS16(gp, lp)                                                     \
  __builtin_amdgcn_global_load_lds(                                           \
      (const __attribute__((address_space(1))) void*)(gp),                    \
      (__attribute__((address_space(3))) void*)(lp), 16, 0, 0)

// ---------------------------------------------------------------------------
// wprep: WT[tap][o][c] bf16 hi/lo with the depthwise Laplacian FOLDED IN.
// ---------------------------------------------------------------------------
__global__ void wprep_kernel(const float* __restrict__ w,
                             unsigned short* __restrict__ wth,
                             unsigned short* __restrict__ wtl) {
  const int idx = blockIdx.x * 256 + threadIdx.x;   // 9*64*64 = 36864
  const int c   = idx & 63;
  const int o   = (idx >> 6) & 63;
  const int tap = idx >> 12;                        // 0..8
  float v = w[((o * 64 + c) * 9) + tap];
  if (o == c) {
    const float lapk[9] = {0.f, 1.f, 0.f, 1.f, -4.f, 1.f, 0.f, 1.f, 0.f};
    v += lapk[tap];
  }
  const unsigned short hi = f2bf(v);
  wth[(tap * 64 + o) * 64 + c] = hi;
  wtl[(tap * 64 + o) * 64 + c] = f2bf(v - bf2f(hi));
}

// ---------------------------------------------------------------------------
// xt: x [b][c][y][x] fp32 -> XT [b][n][c] bf16 hi/lo, swizzled like fh.
// ---------------------------------------------------------------------------
__global__ __launch_bounds__(256) void xt_kernel(
    const float* __restrict__ xin,
    unsigned short* __restrict__ xth, unsigned short* __restrict__ xtl) {
  __shared__ float XL[64][65];
  const int tid = threadIdx.x;
  const int y = blockIdx.x, b = blockIdx.y;
  const int xq = tid & 15, cw = tid >> 4;
  const float* xb = xin + (size_t)b * CC * NPIX + y * WW;
#pragma unroll
  for (int p = 0; p < 4; ++p) {
    const int c = p * 16 + cw;
    const float4 v = *(const float4*)(xb + (size_t)c * NPIX + xq * 4);
    XL[c][xq * 4 + 0] = v.x; XL[c][xq * 4 + 1] = v.y;
    XL[c][xq * 4 + 2] = v.z; XL[c][xq * 4 + 3] = v.w;
  }
  __syncthreads();
  const int px = tid & 63, cp = tid >> 6;
  const size_t nb = ((size_t)b * NPIX + y * WW + px) * CC;
  ushort8 vh[2], vl[2];
#pragma unroll
  for (int j = 0; j < 16; ++j) {
    const float v = XL[cp * 16 + j][px];
    const unsigned short hh = f2bf(v);
    vh[j >> 3][j & 7] = hh;
    vl[j >> 3][j & 7] = f2bf(v - bf2f(hh));
  }
#pragma unroll
  for (int k = 0; k < 2; ++k) {
    const int ch = cp * 2 + k;
    const int off = ((ch ^ (px & 7)) << 3);
    *(ushort8*)(xth + nb + off) = vh[k];
    *(ushort8*)(xtl + nb + off) = vl[k];
  }
}

// ---------------------------------------------------------------------------
// conv_mfma: implicit-GEMM conv (unchanged from round 7).
// ---------------------------------------------------------------------------
__global__ __launch_bounds__(256, 2) void conv_mfma(
    const unsigned short* __restrict__ xth,
    const unsigned short* __restrict__ xtl,
    const unsigned short* __restrict__ wth,
    const unsigned short* __restrict__ wtl,
    unsigned short* __restrict__ fh, unsigned short* __restrict__ fl,
    unsigned short* __restrict__ fv) {
  __shared__ __align__(16) unsigned short XS[6 * 4096];

  const int tid  = threadIdx.x;
  const int lane = tid & 63;
  const int wave = tid >> 6;
  const int r16  = lane & 15;
  const int quad = lane >> 4;
  const int y = blockIdx.x, b = blockIdx.y;

#pragma unroll
  for (int r = 0; r < 3; ++r) {
    const int yy = min(max(y - 1 + r, 0), HH - 1);
    const unsigned short* sh = xth + ((size_t)b * NPIX + yy * WW) * CC;
    const unsigned short* sl = xtl + ((size_t)b * NPIX + yy * WW) * CC;
    GLD_LDS16(sh + tid * 8,        &XS[r * 4096 + tid * 8]);
    GLD_LDS16(sh + 2048 + tid * 8, &XS[r * 4096 + 2048 + tid * 8]);
    GLD_LDS16(sl + tid * 8,        &XS[(3 + r) * 4096 + tid * 8]);
    GLD_LDS16(sl + 2048 + tid * 8, &XS[(3 + r) * 4096 + 2048 + tid * 8]);
  }
  __syncthreads();

  floatx4 acc[4];
#pragma unroll
  for (int t = 0; t < 4; ++t) acc[t] = (floatx4){0.f, 0.f, 0.f, 0.f};
  const bf16x8 ZF = {0, 0, 0, 0, 0, 0, 0, 0};
  const int og = wave * 16 + r16;

#pragma unroll
  for (int tap = 0; tap < 9; ++tap) {
    const int ky = tap / 3, kx = tap % 3;
    const int yy = y + ky - 1;
    if (yy < 0 || yy >= HH) continue;
    const unsigned short* wt = wth + ((tap * 64 + og) << 6);
    const unsigned short* wl = wtl + ((tap * 64 + og) << 6);
    const bf16x8 Wh0 = *(const bf16x8*)(wt + quad * 8);
    const bf16x8 Wh1 = *(const bf16x8*)(wt + 32 + quad * 8);
    const bf16x8 Wl0 = *(const bf16x8*)(wl + quad * 8);
    const bf16x8 Wl1 = *(const bf16x8*)(wl + 32 + quad * 8);
#pragma unroll
    for (int t = 0; t < 4; ++t) {
      const int px = t * 16 + r16 + kx - 1;
      const bool ok = (px >= 0) && (px < WW);
      const int pxc = ok ? px : 0;
      const int bh = ky * 4096 + pxc * 64;
      const int bl = bh + 3 * 4096;
      const int o0 = ((quad ^ (pxc & 7)) << 3);
      const int o1 = (((4 + quad) ^ (pxc & 7)) << 3);
      bf16x8 Ah0 = *(const bf16x8*)(XS + bh + o0);
      bf16x8 Ah1 = *(const bf16x8*)(XS + bh + o1);
      bf16x8 Al0 = *(const bf16x8*)(XS + bl + o0);
      bf16x8 Al1 = *(const bf16x8*)(XS + bl + o1);
      if (!ok) { Ah0 = ZF; Ah1 = ZF; Al0 = ZF; Al1 = ZF; }
      acc[t] = __builtin_amdgcn_mfma_f32_16x16x32_bf16(Ah0, Wh0, acc[t], 0, 0, 0);
      acc[t] = __builtin_amdgcn_mfma_f32_16x16x32_bf16(Ah1, Wh1, acc[t], 0, 0, 0);
      acc[t] = __builtin_amdgcn_mfma_f32_16x16x32_bf16(Ah0, Wl0, acc[t], 0, 0, 0);
      acc[t] = __builtin_amdgcn_mfma_f32_16x16x32_bf16(Ah1, Wl1, acc[t], 0, 0, 0);
      acc[t] = __builtin_amdgcn_mfma_f32_16x16x32_bf16(Al0, Wh0, acc[t], 0, 0, 0);
      acc[t] = __builtin_amdgcn_mfma_f32_16x16x32_bf16(Al1, Wh1, acc[t], 0, 0, 0);
    }
  }

#pragma unroll
  for (int t = 0; t < 4; ++t)
#pragma unroll
    for (int r = 0; r < 4; ++r) {
      const int key = t * 16 + quad * 4 + r;
      const int n = y * WW + key;
      const float v = acc[t][r];
      const unsigned short hi = f2bf(v);
      const unsigned short lo = f2bf(v - bf2f(hi));
      fh[((size_t)b * NPIX + n) * CC + swzoff(n, og)] = hi;
      fl[((size_t)b * NPIX + n) * CC + swzoff(n, og)] = lo;
      fv[(((size_t)b * (NPIX >> 6) + y) * CC + og) * 64 + swzvslot(key, og)] = hi;
    }
}

// ---------------------------------------------------------------------------
// 2x2 average pool on swizzled layout (unchanged).
// ---------------------------------------------------------------------------
__global__ void pool2_kernel(const unsigned short* __restrict__ in_h,
                             const unsigned short* __restrict__ in_l,
                             unsigned short* __restrict__ out_h,
                             unsigned short* __restrict__ out_l,
                             unsigned short* __restrict__ out_v, int hw_out) {
  const int idx = blockIdx.x * blockDim.x + threadIdx.x;
  const int c  = idx & 63;
  const int t  = idx >> 6;
  const int xo = t % hw_out;
  const int r  = t / hw_out;
  const int yo = r % hw_out;
  const int b  = r / hw_out;
  const int win = 2 * hw_out;
  const size_t ibase = (size_t)b * win * win * CC;
  float s = 0.f;
#pragma unroll
  for (int dy = 0; dy < 2; ++dy)
#pragma unroll
    for (int dx = 0; dx < 2; ++dx) {
      const int nin = (2*yo+dy) * win + (2*xo+dx);
      const size_t a = ibase + (size_t)nin * CC + swzoff(nin, c);
      s += bf2f(in_h[a]) + bf2f(in_l[a]);
    }
  const float vv = 0.25f * s;
  const unsigned short hi = f2bf(vv);
  const unsigned short lo = f2bf(vv - bf2f(hi));
  const int nout = yo * hw_out + xo;
  const int Nout = hw_out * hw_out;
  const size_t ob = ((size_t)b * Nout + nout) * CC + swzoff(nout, c);
  out_h[ob] = hi;
  out_l[ob] = lo;
  out_v[(((size_t)b * (Nout >> 6) + (nout >> 6)) * CC + c) * 64
        + swzvslot(nout & 63, c)] = hi;
}

// ---------------------------------------------------------------------------
// MFMA flash attention, templated on <NH, KS>.
//   NH = 16-row Q-halves per wave. K/V LDS reads are amortized over NH
//   halves (NH=4 -> 0.5KB LDS/query/tile vs 0.875 at NH=2 — round-9
//   counters: MfmaUtil 33/VALU 34, DS-read-bound). Halves go through the
//   shared per-wave Pt sequentially (per-wave LDS is in-order -> WAR safe).
//   KS = key-split; fixed-shift softmax makes partials combine by ADDITION.
//   KS>1: write raw O partials in BF16 (+l fp32); final combines. KS==1:
//   normalized fp32 out directly.
// ---------------------------------------------------------------------------
#define STR 72   // P-tile LDS row stride (shorts); 144B keeps b128 aligned

template <int NH, int KS>
__global__ __launch_bounds__(256, 2) void attn_mfma(
    const unsigned short* __restrict__ fh,
    const unsigned short* __restrict__ fl,
    const unsigned short* __restrict__ fv,
    float* __restrict__ outF, unsigned short* __restrict__ outB,
    float* __restrict__ outL, int N) {
  __shared__ __align__(16) unsigned short KVT[2][3 * 4096];
  __shared__ __align__(16) unsigned short Pt[4][16 * STR];

  const int tid  = threadIdx.x;
  const int lane = tid & 63;
  const int wave = tid >> 6;
  const int b    = blockIdx.x & 7;              // XCD-local batch grouping
  const int rest = blockIdx.x >> 3;
  const int nq   = N / (64 * NH);
  const int qt   = rest % nq;
  const int ks   = rest / nq;                   // 0..KS-1
  const int q0   = qt * (64 * NH) + wave * (16 * NH);
  const int nt   = (N >> 6) / KS;
  const int t0   = ks * nt;
  const int r16  = lane & 15;
  const int quad = lane >> 4;
  const int swb  = r16 & 7;

  const unsigned short* fhB = fh + (size_t)b * N * CC;
  const unsigned short* flB = fl + (size_t)b * N * CC;
  const unsigned short* fvB = fv + (size_t)b * N * CC;   // tile-major V^T

  // ---- stage first tile via DMA: 24 chunks of 512 shorts; wave takes 6 ----
  {
    const size_t tb = (size_t)t0 * 4096;
#pragma unroll
    for (int j = 0; j < 6; ++j) {
      const int cid = wave * 6 + j;
      const int arr = cid >> 3, sub = (cid & 7) << 9;
      const unsigned short* g =
          (arr == 0 ? fhB : arr == 1 ? flB : fvB) + tb + sub + lane * 8;
      GLD_LDS16(g, &KVT[0][arr * 4096 + sub + lane * 8]);
    }
  }

  // ---- Q fragments per half: scale by log2e, re-split hi/lo, compute M ----
  bf16x8 Qh[NH][2], Ql[NH][2];
  float Mq[NH][4];
#pragma unroll
  for (int h = 0; h < NH; ++h) {
    float Mpart = 0.f;
#pragma unroll
    for (int kss = 0; kss < 2; ++kss) {
      const size_t off = (size_t)(q0 + h * 16 + r16) * CC
                         + ((((kss << 2) + quad) ^ swb) << 3);
      const bf16x8 hh = *(const bf16x8*)(fhB + off);
      const bf16x8 ll = *(const bf16x8*)(flB + off);
      bf16x8 sh, sl;
#pragma unroll
      for (int j = 0; j < 8; ++j) {
        const float f = bf2f((unsigned short)hh[j]) + bf2f((unsigned short)ll[j]);
        const float g = f * LOG2E;
        const unsigned short gh = f2bf(g);
        sh[j] = (short)gh;
        sl[j] = (short)f2bf(g - bf2f(gh));
        Mpart += g * f;                  // = log2e * sum f^2 (partial)
      }
      Qh[h][kss] = sh;
      Ql[h][kss] = sl;
    }
    Mpart += __shfl_xor(Mpart, 16, 64);
    Mpart += __shfl_xor(Mpart, 32, 64);  // per-row |q|^2*log2e at lane r16
#pragma unroll
    for (int r = 0; r < 4; ++r) Mq[h][r] = __shfl(Mpart, quad * 4 + r, 64);
  }

  floatx4 O[NH][4];
  float lrun[NH][4];
#pragma unroll
  for (int h = 0; h < NH; ++h)
#pragma unroll
    for (int ch = 0; ch < 4; ++ch) {
      O[h][ch] = (floatx4){0.f, 0.f, 0.f, 0.f};
      lrun[h][ch] = 0.f;
    }
  unsigned short* pt = Pt[wave];

  int koff[2];
#pragma unroll
  for (int kss = 0; kss < 2; ++kss) koff[kss] = (((kss << 2) + quad) ^ swb) << 3;

  for (int t = 0; t < nt; ++t) {
    const int cur = t & 1;
    __syncthreads();                    // drains DMA for tile t, syncs block
    if (t + 1 < nt) {                   // issue DMA for tile t+1 now
      const size_t tb = (size_t)(t0 + t + 1) * 4096;
#pragma unroll
      for (int j = 0; j < 6; ++j) {
        const int cid = wave * 6 + j;
        const int arr = cid >> 3, sub = (cid & 7) << 9;
        const unsigned short* g =
            (arr == 0 ? fhB : arr == 1 ? flB : fvB) + tb + sub + lane * 8;
        GLD_LDS16(g, &KVT[cur ^ 1][arr * 4096 + sub + lane * 8]);
      }
    }
    const unsigned short* kh = &KVT[cur][0];
    const unsigned short* kl = &KVT[cur][4096];
    const unsigned short* vt = &KVT[cur][8192];

    // ---- S-tiles: K-frags read once, shared across all NH halves ----
    floatx4 S[NH][4];
#pragma unroll
    for (int tt = 0; tt < 4; ++tt) {
      const int kbase = (tt * 16 + r16) * 64;
      const bf16x8 Kh0 = *(const bf16x8*)(kh + kbase + koff[0]);
      const bf16x8 Kh1 = *(const bf16x8*)(kh + kbase + koff[1]);
      const bf16x8 Kl0 = *(const bf16x8*)(kl + kbase + koff[0]);
      const bf16x8 Kl1 = *(const bf16x8*)(kl + kbase + koff[1]);
#pragma unroll
      for (int h = 0; h < NH; ++h) {
        floatx4 s = (floatx4){0.f, 0.f, 0.f, 0.f};
        s = __builtin_amdgcn_mfma_f32_16x16x32_bf16(Qh[h][0], Kh0, s, 0, 0, 0);
        s = __builtin_amdgcn_mfma_f32_16x16x32_bf16(Qh[h][1], Kh1, s, 0, 0, 0);
        s = __builtin_amdgcn_mfma_f32_16x16x32_bf16(Ql[h][0], Kh0, s, 0, 0, 0);
        s = __builtin_amdgcn_mfma_f32_16x16x32_bf16(Ql[h][1], Kh1, s, 0, 0, 0);
        s = __builtin_amdgcn_mfma_f32_16x16x32_bf16(Qh[h][0], Kl0, s, 0, 0, 0);
        s = __builtin_amdgcn_mfma_f32_16x16x32_bf16(Qh[h][1], Kl1, s, 0, 0, 0);
        S[h][tt] = s;
      }
    }

    // ---- per half: fixed-shift softmax, P round-trip (shared Pt rows) ----
    bf16x8 Pf[NH][2];
#pragma unroll
    for (int h = 0; h < NH; ++h) {
#pragma unroll
      for (int r = 0; r < 4; ++r) {
        float ls = 0.f;
#pragma unroll
        for (int tt = 0; tt < 4; ++tt) {
          const float p = __builtin_amdgcn_exp2f(S[h][tt][r] - Mq[h][r]);
          S[h][tt][r] = p;
          ls += p;
        }
        lrun[h][r] += ls;
      }
#pragma unroll
      for (int tt = 0; tt < 4; ++tt)
#pragma unroll
        for (int r = 0; r < 4; ++r)
          pt[(quad * 4 + r) * STR + tt * 16 + r16] = f2bf(S[h][tt][r]);
#pragma unroll
      for (int kss = 0; kss < 2; ++kss)
        Pf[h][kss] = *(const bf16x8*)(pt + r16 * STR + kss * 32 + quad * 8);
    }

    // ---- O += P*V: V-frags read once, shared across all NH halves ----
#pragma unroll
    for (int kss = 0; kss < 2; ++kss)
#pragma unroll
      for (int ch = 0; ch < 4; ++ch) {
        const bf16x8 Vf = *(const bf16x8*)(vt + (ch * 16 + r16) * 64 + koff[kss]);
#pragma unroll
        for (int h = 0; h < NH; ++h)
          O[h][ch] = __builtin_amdgcn_mfma_f32_16x16x32_bf16(Pf[h][kss], Vf,
                                                            O[h][ch], 0, 0, 0);
      }
  }

  // ---- epilogue ----
#pragma unroll
  for (int h = 0; h < NH; ++h) {
#pragma unroll
    for (int r = 0; r < 4; ++r) {
      float lt = lrun[h][r];
      lt += __shfl_xor(lt, 1, 16);
      lt += __shfl_xor(lt, 2, 16);
      lt += __shfl_xor(lt, 4, 16);
      lt += __shfl_xor(lt, 8, 16);
      if (KS == 1) {
        lrun[h][r] = 1.f / lt;
      } else if (r16 == 0) {
        outL[(size_t)ks * BB * N + (size_t)b * N + q0 + h * 16 + quad * 4 + r] = lt;
      }
    }
#pragma unroll
    for (int ch = 0; ch < 4; ++ch)
#pragma unroll
      for (int r = 0; r < 4; ++r) {
        const size_t qi = (size_t)b * N + q0 + h * 16 + quad * 4 + r;
        if (KS == 1) {
          outF[qi * CC + ch * 16 + r16] = O[h][ch][r] * lrun[h][r];
        } else {
          outB[(size_t)ks * BB * N * CC + qi * CC + ch * 16 + r16] =
              f2bf(O[h][ch][r]);
        }
      }
  }
}

// ---------------------------------------------------------------------------
// out[b][c][y][x] = x + attn1 + bilinear_up2(attn2) + bilinear_up4(attn4)
// attn1/attn2 arrive as 4 split-K partials (raw O bf16 + l fp32); combine:
// value = (sum O_ks) / (sum l_ks). Scale-4 arrives normalized fp32 (a4).
// ---------------------------------------------------------------------------
__global__ __launch_bounds__(256) void final_kernel(
    const float* __restrict__ xin,
    const unsigned short* __restrict__ Op1, const float* __restrict__ Lp1,
    const unsigned short* __restrict__ Op2, const float* __restrict__ Lp2,
    const float* __restrict__ a4, float* __restrict__ out) {
  const int xc = threadIdx.x & 63;
  const int yl = threadIdx.x >> 6;
  const int y  = blockIdx.x * 4 + yl;
  const int c  = blockIdx.y;
  const int b  = blockIdx.z;

  const size_t S1 = (size_t)BB * NPIX * CC;
  const size_t T1 = (size_t)BB * NPIX;
  const size_t S2 = (size_t)BB * 1024 * CC;
  const size_t T2 = (size_t)BB * 1024;

  float r = xin[(((size_t)b * CC + c) * HH + y) * WW + xc];

  {  // scale 1: combine 4 split-K partials
    const int n = y * WW + xc;
    float Ov = 0.f, lv = 0.f;
#pragma unroll
    for (int ks = 0; ks < 4; ++ks) {
      Ov += bf2f(Op1[ks * S1 + ((size_t)b * NPIX + n) * CC + c]);
      lv += Lp1[ks * T1 + (size_t)b * NPIX + n];
    }
    r += Ov / lv;
  }
  {  // scale 2: 32x32 source, 4 partials combined per tap. src = y/2 - 0.25
    const float ty = y * 0.5f - 0.25f;
    const float tx = xc * 0.5f - 0.25f;
    const int iy = (int)floorf(ty), ix = (int)floorf(tx);
    const float wy = ty - iy, wx = tx - ix;
    const int iy0 = max(iy, 0), iy1 = min(iy + 1, 31);
    const int ix0 = max(ix, 0), ix1 = min(ix + 1, 31);
    auto val = [&](int p) {
      float Ov = 0.f, lv = 0.f;
#pragma unroll
      for (int ks = 0; ks < 4; ++ks) {
        Ov += bf2f(Op2[ks * S2 + ((size_t)b * 1024 + p) * CC + c]);
        lv += Lp2[ks * T2 + (size_t)b * 1024 + p];
      }
      return Ov / lv;
    };
    const float v00 = val(iy0 * 32 + ix0), v01 = val(iy0 * 32 + ix1);
    const float v10 = val(iy1 * 32 + ix0), v11 = val(iy1 * 32 + ix1);
    r += (1.f-wy)*((1.f-wx)*v00 + wx*v01) + wy*((1.f-wx)*v10 + wx*v11);
  }
  {  // scale 4: 16x16 source, already normalized. src = y/4 - 0.375
    const float ty = y * 0.25f - 0.375f;
    const float tx = xc * 0.25f - 0.375f;
    const int iy = (int)floorf(ty), ix = (int)floorf(tx);
    const float wy = ty - iy, wx = tx - ix;
    const int iy0 = max(iy, 0), iy1 = min(iy + 1, 15);
    const int ix0 = max(ix, 0), ix1 = min(ix + 1, 15);
    const float* base = a4 + (size_t)b * 256 * 64 + c;
    const float v00 = base[(iy0*16+ix0)*64], v01 = base[(iy0*16+ix1)*64];
    const float v10 = base[(iy1*16+ix0)*64], v11 = base[(iy1*16+ix1)*64];
    r += (1.f-wy)*((1.f-wx)*v00 + wx*v01) + wy*((1.f-wx)*v10 + wx*v11);
  }
  out[(((size_t)b * CC + c) * HH + y) * WW + xc] = r;
}

// ---------------------------------------------------------------------------
extern "C" void kernel_launch(void* const* d_in, const int* in_sizes, int n_in,
                              void* d_out, int out_size, void* d_ws,
                              size_t ws_size, hipStream_t stream) {
  const float* x = (const float*)d_in[0];
  const float* w = (const float*)d_in[1];
  float* out = (float*)d_out;

  unsigned short* fh1 = (unsigned short*)d_ws;            // [8][4096][64] swz
  unsigned short* fl1 = fh1 + (size_t)BB*NPIX*CC;
  unsigned short* fv1 = fl1 + (size_t)BB*NPIX*CC;         // tile-major V^T
  unsigned short* fh2 = fv1 + (size_t)BB*NPIX*CC;         // [8][1024][64]
  unsigned short* fl2 = fh2 + (size_t)BB*1024*CC;
  unsigned short* fv2 = fl2 + (size_t)BB*1024*CC;
  unsigned short* fh4 = fv2 + (size_t)BB*1024*CC;         // [8][256][64]
  unsigned short* fl4 = fh4 + (size_t)BB*256*CC;
  unsigned short* fv4 = fl4 + (size_t)BB*256*CC;
  unsigned short* Op1 = fv4 + (size_t)BB*256*CC;          // [4][8][4096][64] bf16
  float* Lp1 = (float*)(Op1 + 4*(size_t)BB*NPIX*CC);      // [4][8][4096]
  unsigned short* Op2 = (unsigned short*)(Lp1 + 4*(size_t)BB*NPIX);  // [4][8][1024][64]
  float* Lp2 = (float*)(Op2 + 4*(size_t)BB*1024*CC);      // [4][8][1024]
  float* a4  = Lp2 + 4*(size_t)BB*1024;                   // [8][256][64] fp32

  // Dead-time aliases (XT dead after conv_mfma; attn1 writes Op1 later)
  unsigned short* xth = (unsigned short*)Op1;             // 4.19 MB
  unsigned short* xtl = xth + (size_t)BB*NPIX*CC;         // 4.19 MB
  unsigned short* wth = (unsigned short*)Op2;             // 72 KB
  unsigned short* wtl = wth + 9*64*64;                    // 72 KB

  wprep_kernel<<<144, 256, 0, stream>>>(w, wth, wtl);
  xt_kernel<<<dim3(64, 8), 256, 0, stream>>>(x, xth, xtl);
  conv_mfma<<<dim3(64, 8), 256, 0, stream>>>(xth, xtl, wth, wtl, fh1, fl1, fv1);
  pool2_kernel<<<(BB*1024*CC)/256, 256, 0, stream>>>(fh1, fl1, fh2, fl2, fv2, 32);
  pool2_kernel<<<(BB*256*CC)/256, 256, 0, stream>>>(fh2, fl2, fh4, fl4, fv4, 16);
  // scale 1: NH=4 (64 q/wave), KS=4 -> 8*(4096/256)*4 = 512 blocks = 2/CU
  attn_mfma<4, 4><<<8 * 16 * 4, 256, 0, stream>>>(fh1, fl1, fv1, nullptr, Op1,
                                                  Lp1, NPIX);
  // scale 2: NH=1, KS=4 -> 8*16*4 = 512 blocks = 2/CU
  attn_mfma<1, 4><<<8 * 16 * 4, 256, 0, stream>>>(fh2, fl2, fv2, nullptr, Op2,
                                                  Lp2, 1024);
  // scale 4: tiny, direct normalized fp32
  attn_mfma<1, 1><<<8 * 4, 256, 0, stream>>>(fh4, fl4, fv4, a4, nullptr,
                                             nullptr, 256);
  final_kernel<<<dim3(16, 64, 8), 256, 0, stream>>>(x, Op1, Lp1, Op2, Lp2, a4, out);
}

// Round 11
// 216.802 us; speedup vs baseline: 1.3211x; 1.3211x over previous
//
#include <hip/hip_runtime.h>
#include <hip/hip_bf16.h>
#include <math.h>

// Problem constants: x [8,64,64,64] fp32 NCHW, W_std [64,64,3,3] fp32 OIHW.
#define BB 8
#define CC 64
#define HH 64
#define WW 64
#define NPIX (HH*WW)   // 4096
#define LOG2E 1.44269504088896340736f

typedef __attribute__((ext_vector_type(8))) short bf16x8;            // MFMA A/B frag
typedef __attribute__((ext_vector_type(4))) float floatx4;           // MFMA C/D frag
typedef __attribute__((ext_vector_type(8))) unsigned short ushort8;  // 16B unit

__device__ inline unsigned short f2bf(float x) {
  __hip_bfloat16 h = __float2bfloat16(x);
  return *reinterpret_cast<unsigned short*>(&h);
}
__device__ inline float bf2f(unsigned short u) {
  __hip_bfloat16 h = *reinterpret_cast<__hip_bfloat16*>(&u);
  return __bfloat162float(h);
}

// XOR swizzle: 16B channel-chunks permuted within each 128B row so MFMA
// fragment reads from LDS (lane stride 128B) spread across all 32 banks.
__device__ inline int swzoff(int n, int c) {
  return (((c >> 3) ^ (n & 7)) << 3) | (c & 7);
}
__device__ inline int swzvslot(int key, int c) {
  return (((key >> 3) ^ (c & 7)) << 3) | (key & 7);
}

// 16B global -> LDS DMA
#define GLD_LDS16(gp, lp)                                                     \
  __builtin_amdgcn_global_load_lds(                                           \
      (const __attribute__((address_space(1))) void*)(gp),                    \
      (__attribute__((address_space(3))) void*)(lp), 16, 0, 0)

// ---------------------------------------------------------------------------
// wprep: WT[tap][o][c] bf16 hi/lo with the depthwise Laplacian FOLDED IN.
// ---------------------------------------------------------------------------
__global__ void wprep_kernel(const float* __restrict__ w,
                             unsigned short* __restrict__ wth,
                             unsigned short* __restrict__ wtl) {
  const int idx = blockIdx.x * 256 + threadIdx.x;   // 9*64*64 = 36864
  const int c   = idx & 63;
  const int o   = (idx >> 6) & 63;
  const int tap = idx >> 12;                        // 0..8
  float v = w[((o * 64 + c) * 9) + tap];
  if (o == c) {
    const float lapk[9] = {0.f, 1.f, 0.f, 1.f, -4.f, 1.f, 0.f, 1.f, 0.f};
    v += lapk[tap];
  }
  const unsigned short hi = f2bf(v);
  wth[(tap * 64 + o) * 64 + c] = hi;
  wtl[(tap * 64 + o) * 64 + c] = f2bf(v - bf2f(hi));
}

// ---------------------------------------------------------------------------
// xt: x [b][c][y][x] fp32 -> XT [b][n][c] bf16 hi/lo, swizzled like fh.
// ---------------------------------------------------------------------------
__global__ __launch_bounds__(256) void xt_kernel(
    const float* __restrict__ xin,
    unsigned short* __restrict__ xth, unsigned short* __restrict__ xtl) {
  __shared__ float XL[64][65];
  const int tid = threadIdx.x;
  const int y = blockIdx.x, b = blockIdx.y;
  const int xq = tid & 15, cw = tid >> 4;
  const float* xb = xin + (size_t)b * CC * NPIX + y * WW;
#pragma unroll
  for (int p = 0; p < 4; ++p) {
    const int c = p * 16 + cw;
    const float4 v = *(const float4*)(xb + (size_t)c * NPIX + xq * 4);
    XL[c][xq * 4 + 0] = v.x; XL[c][xq * 4 + 1] = v.y;
    XL[c][xq * 4 + 2] = v.z; XL[c][xq * 4 + 3] = v.w;
  }
  __syncthreads();
  const int px = tid & 63, cp = tid >> 6;
  const size_t nb = ((size_t)b * NPIX + y * WW + px) * CC;
  ushort8 vh[2], vl[2];
#pragma unroll
  for (int j = 0; j < 16; ++j) {
    const float v = XL[cp * 16 + j][px];
    const unsigned short hh = f2bf(v);
    vh[j >> 3][j & 7] = hh;
    vl[j >> 3][j & 7] = f2bf(v - bf2f(hh));
  }
#pragma unroll
  for (int k = 0; k < 2; ++k) {
    const int ch = cp * 2 + k;
    const int off = ((ch ^ (px & 7)) << 3);
    *(ushort8*)(xth + nb + off) = vh[k];
    *(ushort8*)(xtl + nb + off) = vl[k];
  }
}

// ---------------------------------------------------------------------------
// conv_mfma: implicit-GEMM conv (unchanged from round 7).
// ---------------------------------------------------------------------------
__global__ __launch_bounds__(256, 2) void conv_mfma(
    const unsigned short* __restrict__ xth,
    const unsigned short* __restrict__ xtl,
    const unsigned short* __restrict__ wth,
    const unsigned short* __restrict__ wtl,
    unsigned short* __restrict__ fh, unsigned short* __restrict__ fl,
    unsigned short* __restrict__ fv) {
  __shared__ __align__(16) unsigned short XS[6 * 4096];

  const int tid  = threadIdx.x;
  const int lane = tid & 63;
  const int wave = tid >> 6;
  const int r16  = lane & 15;
  const int quad = lane >> 4;
  const int y = blockIdx.x, b = blockIdx.y;

#pragma unroll
  for (int r = 0; r < 3; ++r) {
    const int yy = min(max(y - 1 + r, 0), HH - 1);
    const unsigned short* sh = xth + ((size_t)b * NPIX + yy * WW) * CC;
    const unsigned short* sl = xtl + ((size_t)b * NPIX + yy * WW) * CC;
    GLD_LDS16(sh + tid * 8,        &XS[r * 4096 + tid * 8]);
    GLD_LDS16(sh + 2048 + tid * 8, &XS[r * 4096 + 2048 + tid * 8]);
    GLD_LDS16(sl + tid * 8,        &XS[(3 + r) * 4096 + tid * 8]);
    GLD_LDS16(sl + 2048 + tid * 8, &XS[(3 + r) * 4096 + 2048 + tid * 8]);
  }
  __syncthreads();

  floatx4 acc[4];
#pragma unroll
  for (int t = 0; t < 4; ++t) acc[t] = (floatx4){0.f, 0.f, 0.f, 0.f};
  const bf16x8 ZF = {0, 0, 0, 0, 0, 0, 0, 0};
  const int og = wave * 16 + r16;

#pragma unroll
  for (int tap = 0; tap < 9; ++tap) {
    const int ky = tap / 3, kx = tap % 3;
    const int yy = y + ky - 1;
    if (yy < 0 || yy >= HH) continue;
    const unsigned short* wt = wth + ((tap * 64 + og) << 6);
    const unsigned short* wl = wtl + ((tap * 64 + og) << 6);
    const bf16x8 Wh0 = *(const bf16x8*)(wt + quad * 8);
    const bf16x8 Wh1 = *(const bf16x8*)(wt + 32 + quad * 8);
    const bf16x8 Wl0 = *(const bf16x8*)(wl + quad * 8);
    const bf16x8 Wl1 = *(const bf16x8*)(wl + 32 + quad * 8);
#pragma unroll
    for (int t = 0; t < 4; ++t) {
      const int px = t * 16 + r16 + kx - 1;
      const bool ok = (px >= 0) && (px < WW);
      const int pxc = ok ? px : 0;
      const int bh = ky * 4096 + pxc * 64;
      const int bl = bh + 3 * 4096;
      const int o0 = ((quad ^ (pxc & 7)) << 3);
      const int o1 = (((4 + quad) ^ (pxc & 7)) << 3);
      bf16x8 Ah0 = *(const bf16x8*)(XS + bh + o0);
      bf16x8 Ah1 = *(const bf16x8*)(XS + bh + o1);
      bf16x8 Al0 = *(const bf16x8*)(XS + bl + o0);
      bf16x8 Al1 = *(const bf16x8*)(XS + bl + o1);
      if (!ok) { Ah0 = ZF; Ah1 = ZF; Al0 = ZF; Al1 = ZF; }
      acc[t] = __builtin_amdgcn_mfma_f32_16x16x32_bf16(Ah0, Wh0, acc[t], 0, 0, 0);
      acc[t] = __builtin_amdgcn_mfma_f32_16x16x32_bf16(Ah1, Wh1, acc[t], 0, 0, 0);
      acc[t] = __builtin_amdgcn_mfma_f32_16x16x32_bf16(Ah0, Wl0, acc[t], 0, 0, 0);
      acc[t] = __builtin_amdgcn_mfma_f32_16x16x32_bf16(Ah1, Wl1, acc[t], 0, 0, 0);
      acc[t] = __builtin_amdgcn_mfma_f32_16x16x32_bf16(Al0, Wh0, acc[t], 0, 0, 0);
      acc[t] = __builtin_amdgcn_mfma_f32_16x16x32_bf16(Al1, Wh1, acc[t], 0, 0, 0);
    }
  }

#pragma unroll
  for (int t = 0; t < 4; ++t)
#pragma unroll
    for (int r = 0; r < 4; ++r) {
      const int key = t * 16 + quad * 4 + r;
      const int n = y * WW + key;
      const float v = acc[t][r];
      const unsigned short hi = f2bf(v);
      const unsigned short lo = f2bf(v - bf2f(hi));
      fh[((size_t)b * NPIX + n) * CC + swzoff(n, og)] = hi;
      fl[((size_t)b * NPIX + n) * CC + swzoff(n, og)] = lo;
      fv[(((size_t)b * (NPIX >> 6) + y) * CC + og) * 64 + swzvslot(key, og)] = hi;
    }
}

// ---------------------------------------------------------------------------
// 2x2 average pool on swizzled layout (unchanged).
// ---------------------------------------------------------------------------
__global__ void pool2_kernel(const unsigned short* __restrict__ in_h,
                             const unsigned short* __restrict__ in_l,
                             unsigned short* __restrict__ out_h,
                             unsigned short* __restrict__ out_l,
                             unsigned short* __restrict__ out_v, int hw_out) {
  const int idx = blockIdx.x * blockDim.x + threadIdx.x;
  const int c  = idx & 63;
  const int t  = idx >> 6;
  const int xo = t % hw_out;
  const int r  = t / hw_out;
  const int yo = r % hw_out;
  const int b  = r / hw_out;
  const int win = 2 * hw_out;
  const size_t ibase = (size_t)b * win * win * CC;
  float s = 0.f;
#pragma unroll
  for (int dy = 0; dy < 2; ++dy)
#pragma unroll
    for (int dx = 0; dx < 2; ++dx) {
      const int nin = (2*yo+dy) * win + (2*xo+dx);
      const size_t a = ibase + (size_t)nin * CC + swzoff(nin, c);
      s += bf2f(in_h[a]) + bf2f(in_l[a]);
    }
  const float vv = 0.25f * s;
  const unsigned short hi = f2bf(vv);
  const unsigned short lo = f2bf(vv - bf2f(hi));
  const int nout = yo * hw_out + xo;
  const int Nout = hw_out * hw_out;
  const size_t ob = ((size_t)b * Nout + nout) * CC + swzoff(nout, c);
  out_h[ob] = hi;
  out_l[ob] = lo;
  out_v[(((size_t)b * (Nout >> 6) + (nout >> 6)) * CC + c) * 64
        + swzvslot(nout & 63, c)] = hi;
}

// ---------------------------------------------------------------------------
// MFMA flash attention, templated on <NH, KS> (unchanged from round 10).
// ---------------------------------------------------------------------------
#define STR 72   // P-tile LDS row stride (shorts); 144B keeps b128 aligned

template <int NH, int KS>
__global__ __launch_bounds__(256, 2) void attn_mfma(
    const unsigned short* __restrict__ fh,
    const unsigned short* __restrict__ fl,
    const unsigned short* __restrict__ fv,
    float* __restrict__ outF, unsigned short* __restrict__ outB,
    float* __restrict__ outL, int N) {
  __shared__ __align__(16) unsigned short KVT[2][3 * 4096];
  __shared__ __align__(16) unsigned short Pt[4][16 * STR];

  const int tid  = threadIdx.x;
  const int lane = tid & 63;
  const int wave = tid >> 6;
  const int b    = blockIdx.x & 7;              // XCD-local batch grouping
  const int rest = blockIdx.x >> 3;
  const int nq   = N / (64 * NH);
  const int qt   = rest % nq;
  const int ks   = rest / nq;                   // 0..KS-1
  const int q0   = qt * (64 * NH) + wave * (16 * NH);
  const int nt   = (N >> 6) / KS;
  const int t0   = ks * nt;
  const int r16  = lane & 15;
  const int quad = lane >> 4;
  const int swb  = r16 & 7;

  const unsigned short* fhB = fh + (size_t)b * N * CC;
  const unsigned short* flB = fl + (size_t)b * N * CC;
  const unsigned short* fvB = fv + (size_t)b * N * CC;   // tile-major V^T

  // ---- stage first tile via DMA: 24 chunks of 512 shorts; wave takes 6 ----
  {
    const size_t tb = (size_t)t0 * 4096;
#pragma unroll
    for (int j = 0; j < 6; ++j) {
      const int cid = wave * 6 + j;
      const int arr = cid >> 3, sub = (cid & 7) << 9;
      const unsigned short* g =
          (arr == 0 ? fhB : arr == 1 ? flB : fvB) + tb + sub + lane * 8;
      GLD_LDS16(g, &KVT[0][arr * 4096 + sub + lane * 8]);
    }
  }

  // ---- Q fragments per half: scale by log2e, re-split hi/lo, compute M ----
  bf16x8 Qh[NH][2], Ql[NH][2];
  float Mq[NH][4];
#pragma unroll
  for (int h = 0; h < NH; ++h) {
    float Mpart = 0.f;
#pragma unroll
    for (int kss = 0; kss < 2; ++kss) {
      const size_t off = (size_t)(q0 + h * 16 + r16) * CC
                         + ((((kss << 2) + quad) ^ swb) << 3);
      const bf16x8 hh = *(const bf16x8*)(fhB + off);
      const bf16x8 ll = *(const bf16x8*)(flB + off);
      bf16x8 sh, sl;
#pragma unroll
      for (int j = 0; j < 8; ++j) {
        const float f = bf2f((unsigned short)hh[j]) + bf2f((unsigned short)ll[j]);
        const float g = f * LOG2E;
        const unsigned short gh = f2bf(g);
        sh[j] = (short)gh;
        sl[j] = (short)f2bf(g - bf2f(gh));
        Mpart += g * f;                  // = log2e * sum f^2 (partial)
      }
      Qh[h][kss] = sh;
      Ql[h][kss] = sl;
    }
    Mpart += __shfl_xor(Mpart, 16, 64);
    Mpart += __shfl_xor(Mpart, 32, 64);  // per-row |q|^2*log2e at lane r16
#pragma unroll
    for (int r = 0; r < 4; ++r) Mq[h][r] = __shfl(Mpart, quad * 4 + r, 64);
  }

  floatx4 O[NH][4];
  float lrun[NH][4];
#pragma unroll
  for (int h = 0; h < NH; ++h)
#pragma unroll
    for (int ch = 0; ch < 4; ++ch) {
      O[h][ch] = (floatx4){0.f, 0.f, 0.f, 0.f};
      lrun[h][ch] = 0.f;
    }
  unsigned short* pt = Pt[wave];

  int koff[2];
#pragma unroll
  for (int kss = 0; kss < 2; ++kss) koff[kss] = (((kss << 2) + quad) ^ swb) << 3;

  for (int t = 0; t < nt; ++t) {
    const int cur = t & 1;
    __syncthreads();                    // drains DMA for tile t, syncs block
    if (t + 1 < nt) {                   // issue DMA for tile t+1 now
      const size_t tb = (size_t)(t0 + t + 1) * 4096;
#pragma unroll
      for (int j = 0; j < 6; ++j) {
        const int cid = wave * 6 + j;
        const int arr = cid >> 3, sub = (cid & 7) << 9;
        const unsigned short* g =
            (arr == 0 ? fhB : arr == 1 ? flB : fvB) + tb + sub + lane * 8;
        GLD_LDS16(g, &KVT[cur ^ 1][arr * 4096 + sub + lane * 8]);
      }
    }
    const unsigned short* kh = &KVT[cur][0];
    const unsigned short* kl = &KVT[cur][4096];
    const unsigned short* vt = &KVT[cur][8192];

    // ---- S-tiles: K-frags read once, shared across all NH halves ----
    floatx4 S[NH][4];
#pragma unroll
    for (int tt = 0; tt < 4; ++tt) {
      const int kbase = (tt * 16 + r16) * 64;
      const bf16x8 Kh0 = *(const bf16x8*)(kh + kbase + koff[0]);
      const bf16x8 Kh1 = *(const bf16x8*)(kh + kbase + koff[1]);
      const bf16x8 Kl0 = *(const bf16x8*)(kl + kbase + koff[0]);
      const bf16x8 Kl1 = *(const bf16x8*)(kl + kbase + koff[1]);
#pragma unroll
      for (int h = 0; h < NH; ++h) {
        floatx4 s = (floatx4){0.f, 0.f, 0.f, 0.f};
        s = __builtin_amdgcn_mfma_f32_16x16x32_bf16(Qh[h][0], Kh0, s, 0, 0, 0);
        s = __builtin_amdgcn_mfma_f32_16x16x32_bf16(Qh[h][1], Kh1, s, 0, 0, 0);
        s = __builtin_amdgcn_mfma_f32_16x16x32_bf16(Ql[h][0], Kh0, s, 0, 0, 0);
        s = __builtin_amdgcn_mfma_f32_16x16x32_bf16(Ql[h][1], Kh1, s, 0, 0, 0);
        s = __builtin_amdgcn_mfma_f32_16x16x32_bf16(Qh[h][0], Kl0, s, 0, 0, 0);
        s = __builtin_amdgcn_mfma_f32_16x16x32_bf16(Qh[h][1], Kl1, s, 0, 0, 0);
        S[h][tt] = s;
      }
    }

    // ---- per half: fixed-shift softmax, P round-trip (shared Pt rows) ----
    bf16x8 Pf[NH][2];
#pragma unroll
    for (int h = 0; h < NH; ++h) {
#pragma unroll
      for (int r = 0; r < 4; ++r) {
        float ls = 0.f;
#pragma unroll
        for (int tt = 0; tt < 4; ++tt) {
          const float p = __builtin_amdgcn_exp2f(S[h][tt][r] - Mq[h][r]);
          S[h][tt][r] = p;
          ls += p;
        }
        lrun[h][r] += ls;
      }
#pragma unroll
      for (int tt = 0; tt < 4; ++tt)
#pragma unroll
        for (int r = 0; r < 4; ++r)
          pt[(quad * 4 + r) * STR + tt * 16 + r16] = f2bf(S[h][tt][r]);
#pragma unroll
      for (int kss = 0; kss < 2; ++kss)
        Pf[h][kss] = *(const bf16x8*)(pt + r16 * STR + kss * 32 + quad * 8);
    }

    // ---- O += P*V: V-frags read once, shared across all NH halves ----
#pragma unroll
    for (int kss = 0; kss < 2; ++kss)
#pragma unroll
      for (int ch = 0; ch < 4; ++ch) {
        const bf16x8 Vf = *(const bf16x8*)(vt + (ch * 16 + r16) * 64 + koff[kss]);
#pragma unroll
        for (int h = 0; h < NH; ++h)
          O[h][ch] = __builtin_amdgcn_mfma_f32_16x16x32_bf16(Pf[h][kss], Vf,
                                                            O[h][ch], 0, 0, 0);
      }
  }

  // ---- epilogue ----
#pragma unroll
  for (int h = 0; h < NH; ++h) {
#pragma unroll
    for (int r = 0; r < 4; ++r) {
      float lt = lrun[h][r];
      lt += __shfl_xor(lt, 1, 16);
      lt += __shfl_xor(lt, 2, 16);
      lt += __shfl_xor(lt, 4, 16);
      lt += __shfl_xor(lt, 8, 16);
      if (KS == 1) {
        lrun[h][r] = 1.f / lt;
      } else if (r16 == 0) {
        outL[(size_t)ks * BB * N + (size_t)b * N + q0 + h * 16 + quad * 4 + r] = lt;
      }
    }
#pragma unroll
    for (int ch = 0; ch < 4; ++ch)
#pragma unroll
      for (int r = 0; r < 4; ++r) {
        const size_t qi = (size_t)b * N + q0 + h * 16 + quad * 4 + r;
        if (KS == 1) {
          outF[qi * CC + ch * 16 + r16] = O[h][ch][r] * lrun[h][r];
        } else {
          outB[(size_t)ks * BB * N * CC + qi * CC + ch * 16 + r16] =
              f2bf(O[h][ch][r]);
        }
      }
  }
}

// ---------------------------------------------------------------------------
// combine: sum KS bf16 O-partials + KS l-partials (coalesced along c),
// normalize, LDS-transpose, write CHANNEL-MAJOR fp32 outC[b][c][n].
// Round-10 post-mortem: final_kernel read partials [n][c] with fixed c ->
// 2 bytes used per 128B line, ~4.3GB L2 line traffic, 107us. This kernel
// reads lines fully (threads 0..3 cover one n-row's 64 c) and hands final
// a coalesced channel-major array.
// Block = one (b, 64-n tile); grid = B*(N/64).
// ---------------------------------------------------------------------------
template <int KS>
__global__ __launch_bounds__(256) void combine_kernel(
    const unsigned short* __restrict__ Op, const float* __restrict__ Lp,
    float* __restrict__ outC, int N) {
  __shared__ float T[64][65];
  const int tid = threadIdx.x;
  const int nt  = N >> 6;
  const int b   = blockIdx.x / nt;
  const int n0  = (blockIdx.x % nt) * 64;
  const int nl  = tid >> 2;            // local n (0..63)
  const int ck  = (tid & 3) * 16;      // c chunk base
  const int n   = n0 + nl;

  float lv = 0.f;
#pragma unroll
  for (int ks = 0; ks < KS; ++ks)
    lv += Lp[(size_t)ks * BB * N + (size_t)b * N + n];
  const float inv = 1.f / lv;

  float v[16];
#pragma unroll
  for (int j = 0; j < 16; ++j) v[j] = 0.f;
#pragma unroll
  for (int ks = 0; ks < KS; ++ks) {
    const unsigned short* src =
        Op + (size_t)ks * BB * N * CC + ((size_t)b * N + n) * CC + ck;
    const ushort8 u0 = *(const ushort8*)(src);
    const ushort8 u1 = *(const ushort8*)(src + 8);
#pragma unroll
    for (int j = 0; j < 8; ++j) {
      v[j]     += bf2f(u0[j]);
      v[8 + j] += bf2f(u1[j]);
    }
  }
#pragma unroll
  for (int j = 0; j < 16; ++j) T[ck + j][nl] = v[j] * inv;
  __syncthreads();

  const int cw = tid >> 2;             // channel row to write
  const int nk = (tid & 3) * 16;       // n chunk
  float* dst = outC + ((size_t)b * CC + cw) * N + n0 + nk;
#pragma unroll
  for (int j = 0; j < 16; j += 4) {
    *(float4*)(dst + j) = make_float4(T[cw][nk + j], T[cw][nk + j + 1],
                                      T[cw][nk + j + 2], T[cw][nk + j + 3]);
  }
}

// ---------------------------------------------------------------------------
// out[b][c][y][x] = x + a1c + bilinear_up2(a2c) + bilinear_up4(a4)
// a1c/a2c are channel-major fp32 (coalesced along x); a4 is [n][c] fp32
// (512KB, L2-resident, tiny contribution).
// ---------------------------------------------------------------------------
__global__ __launch_bounds__(256) void final_kernel(
    const float* __restrict__ xin,
    const float* __restrict__ a1c, const float* __restrict__ a2c,
    const float* __restrict__ a4, float* __restrict__ out) {
  const int xc = threadIdx.x & 63;
  const int yl = threadIdx.x >> 6;
  const int y  = blockIdx.x * 4 + yl;
  const int c  = blockIdx.y;
  const int b  = blockIdx.z;

  float r = xin[(((size_t)b * CC + c) * HH + y) * WW + xc];
  r += a1c[((size_t)b * CC + c) * NPIX + y * WW + xc];

  {  // scale 2: 32x32 channel-major source. src = y/2 - 0.25
    const float ty = y * 0.5f - 0.25f;
    const float tx = xc * 0.5f - 0.25f;
    const int iy = (int)floorf(ty), ix = (int)floorf(tx);
    const float wy = ty - iy, wx = tx - ix;
    const int iy0 = max(iy, 0), iy1 = min(iy + 1, 31);
    const int ix0 = max(ix, 0), ix1 = min(ix + 1, 31);
    const float* base = a2c + ((size_t)b * CC + c) * 1024;
    const float v00 = base[iy0 * 32 + ix0], v01 = base[iy0 * 32 + ix1];
    const float v10 = base[iy1 * 32 + ix0], v11 = base[iy1 * 32 + ix1];
    r += (1.f-wy)*((1.f-wx)*v00 + wx*v01) + wy*((1.f-wx)*v10 + wx*v11);
  }
  {  // scale 4: 16x16 [n][c] source (already normalized). src = y/4 - 0.375
    const float ty = y * 0.25f - 0.375f;
    const float tx = xc * 0.25f - 0.375f;
    const int iy = (int)floorf(ty), ix = (int)floorf(tx);
    const float wy = ty - iy, wx = tx - ix;
    const int iy0 = max(iy, 0), iy1 = min(iy + 1, 15);
    const int ix0 = max(ix, 0), ix1 = min(ix + 1, 15);
    const float* base = a4 + (size_t)b * 256 * 64 + c;
    const float v00 = base[(iy0*16+ix0)*64], v01 = base[(iy0*16+ix1)*64];
    const float v10 = base[(iy1*16+ix0)*64], v11 = base[(iy1*16+ix1)*64];
    r += (1.f-wy)*((1.f-wx)*v00 + wx*v01) + wy*((1.f-wx)*v10 + wx*v11);
  }
  out[(((size_t)b * CC + c) * HH + y) * WW + xc] = r;
}

// ---------------------------------------------------------------------------
extern "C" void kernel_launch(void* const* d_in, const int* in_sizes, int n_in,
                              void* d_out, int out_size, void* d_ws,
                              size_t ws_size, hipStream_t stream) {
  const float* x = (const float*)d_in[0];
  const float* w = (const float*)d_in[1];
  float* out = (float*)d_out;

  unsigned short* fh1 = (unsigned short*)d_ws;            // [8][4096][64] swz
  unsigned short* fl1 = fh1 + (size_t)BB*NPIX*CC;
  unsigned short* fv1 = fl1 + (size_t)BB*NPIX*CC;         // tile-major V^T
  unsigned short* fh2 = fv1 + (size_t)BB*NPIX*CC;         // [8][1024][64]
  unsigned short* fl2 = fh2 + (size_t)BB*1024*CC;
  unsigned short* fv2 = fl2 + (size_t)BB*1024*CC;
  unsigned short* fh4 = fv2 + (size_t)BB*1024*CC;         // [8][256][64]
  unsigned short* fl4 = fh4 + (size_t)BB*256*CC;
  unsigned short* fv4 = fl4 + (size_t)BB*256*CC;
  unsigned short* Op1 = fv4 + (size_t)BB*256*CC;          // [4][8][4096][64] bf16
  float* Lp1 = (float*)(Op1 + 4*(size_t)BB*NPIX*CC);      // [4][8][4096]
  unsigned short* Op2 = (unsigned short*)(Lp1 + 4*(size_t)BB*NPIX);  // [4][8][1024][64]
  float* Lp2 = (float*)(Op2 + 4*(size_t)BB*1024*CC);      // [4][8][1024]
  float* a4  = Lp2 + 4*(size_t)BB*1024;                   // [8][256][64] fp32

  // Dead-time aliases (zero workspace growth):
  //   XT/WT (dead after conv_mfma) alias Op1/Op2 (written by attn later)
  //   a1c (combine1 out) aliases fh1+fl1 (dead after attn1)
  //   a2c (combine2 out) aliases fh2+fl2 (dead after attn2)
  unsigned short* xth = (unsigned short*)Op1;             // 4.19 MB
  unsigned short* xtl = xth + (size_t)BB*NPIX*CC;         // 4.19 MB
  unsigned short* wth = (unsigned short*)Op2;             // 72 KB
  unsigned short* wtl = wth + 9*64*64;                    // 72 KB
  float* a1c = (float*)fh1;                               // [8][64][4096] fp32
  float* a2c = (float*)fh2;                               // [8][64][1024] fp32

  wprep_kernel<<<144, 256, 0, stream>>>(w, wth, wtl);
  xt_kernel<<<dim3(64, 8), 256, 0, stream>>>(x, xth, xtl);
  conv_mfma<<<dim3(64, 8), 256, 0, stream>>>(xth, xtl, wth, wtl, fh1, fl1, fv1);
  pool2_kernel<<<(BB*1024*CC)/256, 256, 0, stream>>>(fh1, fl1, fh2, fl2, fv2, 32);
  pool2_kernel<<<(BB*256*CC)/256, 256, 0, stream>>>(fh2, fl2, fh4, fl4, fv4, 16);
  // scale 1: NH=4 (64 q/wave), KS=4 -> 512 blocks = 2/CU
  attn_mfma<4, 4><<<8 * 16 * 4, 256, 0, stream>>>(fh1, fl1, fv1, nullptr, Op1,
                                                  Lp1, NPIX);
  // scale 2: NH=1, KS=4 -> 512 blocks = 2/CU
  attn_mfma<1, 4><<<8 * 16 * 4, 256, 0, stream>>>(fh2, fl2, fv2, nullptr, Op2,
                                                  Lp2, 1024);
  // scale 4: tiny, direct normalized fp32
  attn_mfma<1, 1><<<8 * 4, 256, 0, stream>>>(fh4, fl4, fv4, a4, nullptr,
                                             nullptr, 256);
  combine_kernel<4><<<BB * (NPIX / 64), 256, 0, stream>>>(Op1, Lp1, a1c, NPIX);
  combine_kernel<4><<<BB * (1024 / 64), 256, 0, stream>>>(Op2, Lp2, a2c, 1024);
  final_kernel<<<dim3(16, 64, 8), 256, 0, stream>>>(x, a1c, a2c, a4, out);
}